// Round 4
// baseline (474.942 us; speedup 1.0000x reference)
//
#include <hip/hip_runtime.h>

#define D 64

static __host__ __device__ inline int alignup(int x) { return (x + 63) & ~63; }

__device__ inline float b2f(unsigned short s) {
    return __uint_as_float(((unsigned int)s) << 16);
}
__device__ inline unsigned short f2b(float f) {
    unsigned int u = __float_as_uint(f);
    unsigned int r = (u + 0x7FFFu + ((u >> 16) & 1u)) >> 16;
    return (unsigned short)r;
}

__global__ void init_deg_cnt(float* __restrict__ wdeg, int* __restrict__ cnt, int n, float fill) {
    int i = blockIdx.x * blockDim.x + threadIdx.x;
    if (i < n) { wdeg[i] = fill; cnt[i] = 0; }
}

__global__ void accum_deg_cnt(const int* __restrict__ row, const float* __restrict__ w,
                              float* __restrict__ wdeg, int* __restrict__ cnt, int E) {
    int e = blockIdx.x * blockDim.x + threadIdx.x;
    if (e < E) {
        int r = row[e];
        atomicAdd(&wdeg[r], w[e]);
        atomicAdd(&cnt[r], 1);
    }
}

__global__ void finalize_dinv(float* __restrict__ wdeg, int n) {
    int i = blockIdx.x * blockDim.x + threadIdx.x;
    if (i < n) {
        float d = wdeg[i];
        wdeg[i] = d > 0.0f ? rsqrtf(d) : 0.0f;
    }
}

// x (f32) -> xb (bf16), 4 elements per thread
__global__ void convert_bf16(const float* __restrict__ x, unsigned short* __restrict__ xb, long nElem) {
    long t = (long)blockIdx.x * blockDim.x + threadIdx.x;
    long i = t * 4;
    if (i + 3 < nElem) {
        float4 v = *(const float4*)(x + i);
        ushort4 o;
        o.x = f2b(v.x); o.y = f2b(v.y); o.z = f2b(v.z); o.w = f2b(v.w);
        *(ushort4*)(xb + i) = o;
    } else {
        for (long k = i; k < nElem; ++k) xb[k] = f2b(x[k]);
    }
}

__global__ void scan_block_sums(const int* __restrict__ cnt, int* __restrict__ bsums, int n) {
    __shared__ int s[256];
    int t = threadIdx.x;
    int i = blockIdx.x * 256 + t;
    s[t] = (i < n) ? cnt[i] : 0;
    __syncthreads();
    for (int st = 128; st > 0; st >>= 1) {
        if (t < st) s[t] += s[t + st];
        __syncthreads();
    }
    if (t == 0) bsums[blockIdx.x] = s[0];
}

__global__ void scan_bsums(int* __restrict__ bsums, int nb) {
    __shared__ int s[1024];
    int t = threadIdx.x;
    s[t] = (t < nb) ? bsums[t] : 0;
    __syncthreads();
    for (int off = 1; off < 1024; off <<= 1) {
        int v = 0;
        if (t >= off) v = s[t - off];
        __syncthreads();
        if (t >= off) s[t] += v;
        __syncthreads();
    }
    if (t < nb) bsums[t] = (t == 0) ? 0 : s[t - 1];
}

__global__ void scan_final(const int* __restrict__ cnt, const int* __restrict__ bsums,
                           int* __restrict__ off, int* __restrict__ cur, int n) {
    __shared__ int s[256];
    int t = threadIdx.x;
    int i = blockIdx.x * 256 + t;
    int v = (i < n) ? cnt[i] : 0;
    s[t] = v;
    __syncthreads();
    for (int o = 1; o < 256; o <<= 1) {
        int u = 0;
        if (t >= o) u = s[t - o];
        __syncthreads();
        if (t >= o) s[t] += u;
        __syncthreads();
    }
    if (i < n) {
        int o0 = bsums[blockIdx.x] + s[t] - v;
        off[i] = o0;
        cur[i] = o0;
    }
}

__global__ void scatter_csr(const int* __restrict__ row, const int* __restrict__ col,
                            const float* __restrict__ w, const float* __restrict__ dinv,
                            int* __restrict__ cur, int* __restrict__ csr_col,
                            float* __restrict__ csr_w, int E) {
    int e = blockIdx.x * blockDim.x + threadIdx.x;
    if (e >= E) return;
    int r = row[e];
    int c = col[e];
    int pos = atomicAdd(&cur[r], 1);
    csr_col[pos] = c;
    csr_w[pos] = dinv[r] * w[e] * dinv[c];
}

// hop 1: gather bf16 features, accumulate f32, write bf16
__global__ void hop_gather_b(const unsigned short* __restrict__ xb, const float* __restrict__ dinv,
                             const int* __restrict__ off, const int* __restrict__ end,
                             const int* __restrict__ csr_col, const float* __restrict__ csr_w,
                             unsigned short* __restrict__ h1b, int n) {
    int t = blockIdx.x * blockDim.x + threadIdx.x;
    int i = t >> 6;
    int lane = t & 63;
    if (i >= n) return;
    float di = dinv[i];
    float a0 = b2f(xb[(long)i * D + lane]) * (di * di);  // self-loop (fill=1)
    float a1 = 0.f, a2 = 0.f, a3 = 0.f;
    int s = off[i], e = end[i];
    for (int base = s; base < e; base += 64) {
        int m = e - base; if (m > 64) m = 64;
        int idx = base + (lane < m ? lane : m - 1);
        int cols = csr_col[idx];
        float ws  = csr_w[idx];
        int p = 0;
        for (; p + 4 <= m; p += 4) {
            int   c0 = __shfl(cols, p, 64),   c1 = __shfl(cols, p+1, 64);
            int   c2 = __shfl(cols, p+2, 64), c3 = __shfl(cols, p+3, 64);
            float w0 = __shfl(ws, p, 64),     w1 = __shfl(ws, p+1, 64);
            float w2 = __shfl(ws, p+2, 64),   w3 = __shfl(ws, p+3, 64);
            a0 += b2f(xb[(long)c0 * D + lane]) * w0;
            a1 += b2f(xb[(long)c1 * D + lane]) * w1;
            a2 += b2f(xb[(long)c2 * D + lane]) * w2;
            a3 += b2f(xb[(long)c3 * D + lane]) * w3;
        }
        for (; p < m; ++p) {
            int c = __shfl(cols, p, 64);
            float wv = __shfl(ws, p, 64);
            a0 += b2f(xb[(long)c * D + lane]) * wv;
        }
    }
    h1b[(long)i * D + lane] = f2b((a0 + a1) + (a2 + a3));
}

// hop 2 fused with projection: gather bf16 h1, f32 accumulate + proj, f32 out
__global__ void hop_gather_proj_b(const unsigned short* __restrict__ h1b, const float* __restrict__ dinv,
                                  const int* __restrict__ off, const int* __restrict__ end,
                                  const int* __restrict__ csr_col, const float* __restrict__ csr_w,
                                  const float* __restrict__ W, const float* __restrict__ bias,
                                  float* __restrict__ out, int n) {
    __shared__ float Wl[D * D];
    __shared__ float bl[D];
    for (int k = threadIdx.x; k < D * D; k += blockDim.x) Wl[k] = W[k];
    if (threadIdx.x < D) bl[threadIdx.x] = bias[threadIdx.x];
    __syncthreads();

    int t = blockIdx.x * blockDim.x + threadIdx.x;
    int i = t >> 6;
    int lane = t & 63;
    if (i >= n) return;

    float di = dinv[i];
    float a0 = b2f(h1b[(long)i * D + lane]) * (di * di);
    float a1 = 0.f, a2 = 0.f, a3 = 0.f;
    int s = off[i], e = end[i];
    for (int base = s; base < e; base += 64) {
        int m = e - base; if (m > 64) m = 64;
        int idx = base + (lane < m ? lane : m - 1);
        int cols = csr_col[idx];
        float ws  = csr_w[idx];
        int p = 0;
        for (; p + 4 <= m; p += 4) {
            int   c0 = __shfl(cols, p, 64),   c1 = __shfl(cols, p+1, 64);
            int   c2 = __shfl(cols, p+2, 64), c3 = __shfl(cols, p+3, 64);
            float w0 = __shfl(ws, p, 64),     w1 = __shfl(ws, p+1, 64);
            float w2 = __shfl(ws, p+2, 64),   w3 = __shfl(ws, p+3, 64);
            a0 += b2f(h1b[(long)c0 * D + lane]) * w0;
            a1 += b2f(h1b[(long)c1 * D + lane]) * w1;
            a2 += b2f(h1b[(long)c2 * D + lane]) * w2;
            a3 += b2f(h1b[(long)c3 * D + lane]) * w3;
        }
        for (; p < m; ++p) {
            int c = __shfl(cols, p, 64);
            float wv = __shfl(ws, p, 64);
            a0 += b2f(h1b[(long)c * D + lane]) * wv;
        }
    }
    float acc = (a0 + a1) + (a2 + a3);

    float y = bl[lane];
    #pragma unroll
    for (int k = 0; k < D; ++k) {
        y += __shfl(acc, k, 64) * Wl[k * D + lane];
    }
    out[(long)i * D + lane] = y;
}

extern "C" void kernel_launch(void* const* d_in, const int* in_sizes, int n_in,
                              void* d_out, int out_size, void* d_ws, size_t ws_size,
                              hipStream_t stream) {
    const float* x    = (const float*)d_in[0];
    const int*   ei   = (const int*)d_in[1];
    const float* ew   = (const float*)d_in[2];
    const float* W    = (const float*)d_in[3];
    const float* bias = (const float*)d_in[4];

    int n = in_sizes[0] / D;   // 100000
    int E = in_sizes[2];       // 1600000
    const int* row = ei;
    const int* col = ei + E;

    float* out = (float*)d_out;

    // workspace layout (4-byte units unless noted)
    float* wdeg    = (float*)d_ws;                   // n (becomes dinv)
    int*   cnt     = (int*)(wdeg + alignup(n));      // n
    int*   bsums   = cnt + alignup(n);               // <=1024
    int*   off     = bsums + 1024;                   // n
    int*   cur     = off + alignup(n);               // n (becomes segment end)
    int*   csr_col = cur + alignup(n);               // E
    float* csr_w   = (float*)(csr_col + alignup(E)); // E
    unsigned short* xb  = (unsigned short*)(csr_w + alignup(E)); // n*D bf16
    unsigned short* h1b = xb + (long)alignup(n) * D;             // n*D bf16

    const float fill = 1.0f;  // IMPROVED = False
    const int blk = 256;
    int nbN = (n + blk - 1) / blk;
    int nbE = (E + blk - 1) / blk;

    init_deg_cnt<<<nbN, blk, 0, stream>>>(wdeg, cnt, n, fill);
    accum_deg_cnt<<<nbE, blk, 0, stream>>>(row, ew, wdeg, cnt, E);
    finalize_dinv<<<nbN, blk, 0, stream>>>(wdeg, n);

    long nElem = (long)n * D;
    int nbC = (int)((nElem / 4 + blk - 1) / blk);
    convert_bf16<<<nbC, blk, 0, stream>>>(x, xb, nElem);

    scan_block_sums<<<nbN, blk, 0, stream>>>(cnt, bsums, n);
    scan_bsums<<<1, 1024, 0, stream>>>(bsums, nbN);
    scan_final<<<nbN, blk, 0, stream>>>(cnt, bsums, off, cur, n);

    scatter_csr<<<nbE, blk, 0, stream>>>(row, col, ew, wdeg, cur, csr_col, csr_w, E);

    int nbWave = (int)((nElem + blk - 1) / blk);
    hop_gather_b<<<nbWave, blk, 0, stream>>>(xb, wdeg, off, cur, csr_col, csr_w, h1b, n);
    hop_gather_proj_b<<<nbWave, blk, 0, stream>>>(h1b, wdeg, off, cur, csr_col, csr_w,
                                                  W, bias, out, n);
}

// Round 5
// 470.487 us; speedup vs baseline: 1.0095x; 1.0095x over previous
//
#include <hip/hip_runtime.h>

#define D 64

static __host__ __device__ inline int alignup(int x) { return (x + 63) & ~63; }

__device__ inline float blo(unsigned int u) { return __uint_as_float(u << 16); }
__device__ inline float bhi(unsigned int u) { return __uint_as_float(u & 0xffff0000u); }
__device__ inline unsigned short f2b(float f) {
    unsigned int u = __float_as_uint(f);
    return (unsigned short)((u + 0x7FFFu + ((u >> 16) & 1u)) >> 16);
}
__device__ inline unsigned int packb(float lo, float hi) {
    return (unsigned int)f2b(lo) | ((unsigned int)f2b(hi) << 16);
}

__global__ void init_deg_cnt(float* __restrict__ wdeg, int* __restrict__ cnt, int n, float fill) {
    int i = blockIdx.x * blockDim.x + threadIdx.x;
    if (i < n) { wdeg[i] = fill; cnt[i] = 0; }
}

__global__ void accum_deg_cnt(const int* __restrict__ row, const float* __restrict__ w,
                              float* __restrict__ wdeg, int* __restrict__ cnt, int E) {
    int e = blockIdx.x * blockDim.x + threadIdx.x;
    if (e < E) {
        int r = row[e];
        atomicAdd(&wdeg[r], w[e]);
        atomicAdd(&cnt[r], 1);
    }
}

__global__ void finalize_dinv(float* __restrict__ wdeg, int n) {
    int i = blockIdx.x * blockDim.x + threadIdx.x;
    if (i < n) {
        float d = wdeg[i];
        wdeg[i] = d > 0.0f ? rsqrtf(d) : 0.0f;
    }
}

__global__ void convert_bf16(const float* __restrict__ x, unsigned short* __restrict__ xb, long nElem) {
    long t = (long)blockIdx.x * blockDim.x + threadIdx.x;
    long i = t * 4;
    if (i + 3 < nElem) {
        float4 v = *(const float4*)(x + i);
        ushort4 o;
        o.x = f2b(v.x); o.y = f2b(v.y); o.z = f2b(v.z); o.w = f2b(v.w);
        *(ushort4*)(xb + i) = o;
    } else {
        for (long k = i; k < nElem; ++k) xb[k] = f2b(x[k]);
    }
}

__global__ void scan_block_sums(const int* __restrict__ cnt, int* __restrict__ bsums, int n) {
    __shared__ int s[256];
    int t = threadIdx.x;
    int i = blockIdx.x * 256 + t;
    s[t] = (i < n) ? cnt[i] : 0;
    __syncthreads();
    for (int st = 128; st > 0; st >>= 1) {
        if (t < st) s[t] += s[t + st];
        __syncthreads();
    }
    if (t == 0) bsums[blockIdx.x] = s[0];
}

__global__ void scan_bsums(int* __restrict__ bsums, int nb) {
    __shared__ int s[1024];
    int t = threadIdx.x;
    s[t] = (t < nb) ? bsums[t] : 0;
    __syncthreads();
    for (int off = 1; off < 1024; off <<= 1) {
        int v = 0;
        if (t >= off) v = s[t - off];
        __syncthreads();
        if (t >= off) s[t] += v;
        __syncthreads();
    }
    if (t < nb) bsums[t] = (t == 0) ? 0 : s[t - 1];
}

__global__ void scan_final(const int* __restrict__ cnt, const int* __restrict__ bsums,
                           int* __restrict__ off, int* __restrict__ cur, int n) {
    __shared__ int s[256];
    int t = threadIdx.x;
    int i = blockIdx.x * 256 + t;
    int v = (i < n) ? cnt[i] : 0;
    s[t] = v;
    __syncthreads();
    for (int o = 1; o < 256; o <<= 1) {
        int u = 0;
        if (t >= o) u = s[t - o];
        __syncthreads();
        if (t >= o) s[t] += u;
        __syncthreads();
    }
    if (i < n) {
        int o0 = bsums[blockIdx.x] + s[t] - v;
        off[i] = o0;
        cur[i] = o0;
    }
}

__global__ void scatter_csr(const int* __restrict__ row, const int* __restrict__ col,
                            const float* __restrict__ w, const float* __restrict__ dinv,
                            int* __restrict__ cur, int* __restrict__ csr_col,
                            float* __restrict__ csr_w, int E) {
    int e = blockIdx.x * blockDim.x + threadIdx.x;
    if (e >= E) return;
    int r = row[e];
    int c = col[e];
    int pos = atomicAdd(&cur[r], 1);
    csr_col[pos] = c;
    csr_w[pos] = dinv[r] * w[e] * dinv[c];
}

// One wave per node. 8 edge-groups x 8 lanes; each lane gathers uint4 = 8 bf16
// columns of its group's edge row -> 8 edges per load instruction. f32 accum,
// shfl_xor tree combines groups once per node; self-loop after combine.
// GATHER_BODY leaves a0..a7 (columns 8q..8q+7) fully combined + self-looped.
#define GATHER_BODY(SRC)                                                        \
    int g = lane >> 3;                                                          \
    int q = lane & 7;                                                           \
    const unsigned int* xw = (const unsigned int*)(SRC);                        \
    float a0=0,a1=0,a2=0,a3=0,a4=0,a5=0,a6=0,a7=0;                              \
    int s = off[i], e = end[i];                                                 \
    for (int base = s; base < e; base += 64) {                                  \
        int m = e - base; if (m > 64) m = 64;                                   \
        int li = lane < m ? lane : m - 1;                                       \
        int cols = csr_col[base + li];                                          \
        float wsv = csr_w[base + li];                                           \
        for (int p = 0; p < m; p += 8) {                                        \
            int idx = p + g;                                                    \
            int srcl = idx < m ? idx : m - 1;                                   \
            int c = __shfl(cols, srcl, 64);                                     \
            float wv = __shfl(wsv, srcl, 64);                                   \
            if (idx >= m) wv = 0.0f;                                            \
            uint4 v = *(const uint4*)(xw + (long)c * 32 + q * 4);               \
            a0 += blo(v.x) * wv; a1 += bhi(v.x) * wv;                           \
            a2 += blo(v.y) * wv; a3 += bhi(v.y) * wv;                           \
            a4 += blo(v.z) * wv; a5 += bhi(v.z) * wv;                           \
            a6 += blo(v.w) * wv; a7 += bhi(v.w) * wv;                           \
        }                                                                       \
    }                                                                           \
    a0 += __shfl_xor(a0, 8, 64); a0 += __shfl_xor(a0, 16, 64); a0 += __shfl_xor(a0, 32, 64); \
    a1 += __shfl_xor(a1, 8, 64); a1 += __shfl_xor(a1, 16, 64); a1 += __shfl_xor(a1, 32, 64); \
    a2 += __shfl_xor(a2, 8, 64); a2 += __shfl_xor(a2, 16, 64); a2 += __shfl_xor(a2, 32, 64); \
    a3 += __shfl_xor(a3, 8, 64); a3 += __shfl_xor(a3, 16, 64); a3 += __shfl_xor(a3, 32, 64); \
    a4 += __shfl_xor(a4, 8, 64); a4 += __shfl_xor(a4, 16, 64); a4 += __shfl_xor(a4, 32, 64); \
    a5 += __shfl_xor(a5, 8, 64); a5 += __shfl_xor(a5, 16, 64); a5 += __shfl_xor(a5, 32, 64); \
    a6 += __shfl_xor(a6, 8, 64); a6 += __shfl_xor(a6, 16, 64); a6 += __shfl_xor(a6, 32, 64); \
    a7 += __shfl_xor(a7, 8, 64); a7 += __shfl_xor(a7, 16, 64); a7 += __shfl_xor(a7, 32, 64); \
    float di = dinv[i]; float di2 = di * di;                                    \
    uint4 sv = *(const uint4*)(xw + (long)i * 32 + q * 4);                      \
    a0 += blo(sv.x) * di2; a1 += bhi(sv.x) * di2;                               \
    a2 += blo(sv.y) * di2; a3 += bhi(sv.y) * di2;                               \
    a4 += blo(sv.z) * di2; a5 += bhi(sv.z) * di2;                               \
    a6 += blo(sv.w) * di2; a7 += bhi(sv.w) * di2;

__global__ void hop_gather_b(const unsigned short* __restrict__ xb, const float* __restrict__ dinv,
                             const int* __restrict__ off, const int* __restrict__ end,
                             const int* __restrict__ csr_col, const float* __restrict__ csr_w,
                             unsigned short* __restrict__ h1b, int n) {
    int t = blockIdx.x * blockDim.x + threadIdx.x;
    int i = t >> 6, lane = t & 63;
    if (i >= n) return;
    GATHER_BODY(xb)
    if (lane < 8) {
        uint4 o;
        o.x = packb(a0, a1); o.y = packb(a2, a3);
        o.z = packb(a4, a5); o.w = packb(a6, a7);
        *(uint4*)((unsigned int*)h1b + (long)i * 32 + q * 4) = o;
    }
}

__global__ void hop_gather_proj_b(const unsigned short* __restrict__ h1b, const float* __restrict__ dinv,
                                  const int* __restrict__ off, const int* __restrict__ end,
                                  const int* __restrict__ csr_col, const float* __restrict__ csr_w,
                                  const float* __restrict__ W, const float* __restrict__ bias,
                                  float* __restrict__ out, int n) {
    __shared__ float Wl[D * D];
    __shared__ float bl[D];
    for (int k = threadIdx.x; k < D * D; k += blockDim.x) Wl[k] = W[k];
    if (threadIdx.x < D) bl[threadIdx.x] = bias[threadIdx.x];
    __syncthreads();

    int t = blockIdx.x * blockDim.x + threadIdx.x;
    int i = t >> 6, lane = t & 63;
    if (i >= n) return;
    GATHER_BODY(h1b)

    // lane q2 (0..7) holds columns 8*q2+j in a_j; broadcast and project.
    float y = bl[lane];
    #pragma unroll
    for (int q2 = 0; q2 < 8; ++q2) {
        y += __shfl(a0, q2, 64) * Wl[(8 * q2 + 0) * D + lane];
        y += __shfl(a1, q2, 64) * Wl[(8 * q2 + 1) * D + lane];
        y += __shfl(a2, q2, 64) * Wl[(8 * q2 + 2) * D + lane];
        y += __shfl(a3, q2, 64) * Wl[(8 * q2 + 3) * D + lane];
        y += __shfl(a4, q2, 64) * Wl[(8 * q2 + 4) * D + lane];
        y += __shfl(a5, q2, 64) * Wl[(8 * q2 + 5) * D + lane];
        y += __shfl(a6, q2, 64) * Wl[(8 * q2 + 6) * D + lane];
        y += __shfl(a7, q2, 64) * Wl[(8 * q2 + 7) * D + lane];
    }
    out[(long)i * D + lane] = y;
}

extern "C" void kernel_launch(void* const* d_in, const int* in_sizes, int n_in,
                              void* d_out, int out_size, void* d_ws, size_t ws_size,
                              hipStream_t stream) {
    const float* x    = (const float*)d_in[0];
    const int*   ei   = (const int*)d_in[1];
    const float* ew   = (const float*)d_in[2];
    const float* W    = (const float*)d_in[3];
    const float* bias = (const float*)d_in[4];

    int n = in_sizes[0] / D;   // 100000
    int E = in_sizes[2];       // 1600000
    const int* row = ei;
    const int* col = ei + E;

    float* out = (float*)d_out;

    float* wdeg    = (float*)d_ws;                   // n (becomes dinv)
    int*   cnt     = (int*)(wdeg + alignup(n));      // n
    int*   bsums   = cnt + alignup(n);               // <=1024
    int*   off     = bsums + 1024;                   // n
    int*   cur     = off + alignup(n);               // n (becomes segment end)
    int*   csr_col = cur + alignup(n);               // E
    float* csr_w   = (float*)(csr_col + alignup(E)); // E
    unsigned short* xb  = (unsigned short*)(csr_w + alignup(E)); // n*D bf16
    unsigned short* h1b = xb + (long)alignup(n) * D;             // n*D bf16

    const float fill = 1.0f;  // IMPROVED = False
    const int blk = 256;
    int nbN = (n + blk - 1) / blk;
    int nbE = (E + blk - 1) / blk;

    init_deg_cnt<<<nbN, blk, 0, stream>>>(wdeg, cnt, n, fill);
    accum_deg_cnt<<<nbE, blk, 0, stream>>>(row, ew, wdeg, cnt, E);
    finalize_dinv<<<nbN, blk, 0, stream>>>(wdeg, n);

    long nElem = (long)n * D;
    int nbC = (int)((nElem / 4 + blk - 1) / blk);
    convert_bf16<<<nbC, blk, 0, stream>>>(x, xb, nElem);

    scan_block_sums<<<nbN, blk, 0, stream>>>(cnt, bsums, n);
    scan_bsums<<<1, 1024, 0, stream>>>(bsums, nbN);
    scan_final<<<nbN, blk, 0, stream>>>(cnt, bsums, off, cur, n);

    scatter_csr<<<nbE, blk, 0, stream>>>(row, col, ew, wdeg, cur, csr_col, csr_w, E);

    int nbWave = (int)((nElem + blk - 1) / blk);
    hop_gather_b<<<nbWave, blk, 0, stream>>>(xb, wdeg, off, cur, csr_col, csr_w, h1b, n);
    hop_gather_proj_b<<<nbWave, blk, 0, stream>>>(h1b, wdeg, off, cur, csr_col, csr_w,
                                                  W, bias, out, n);
}

// Round 6
// 446.778 us; speedup vs baseline: 1.0630x; 1.0531x over previous
//
#include <hip/hip_runtime.h>

#define D 64

static __host__ __device__ inline int alignup(int x) { return (x + 63) & ~63; }

__device__ inline float blo(unsigned int u) { return __uint_as_float(u << 16); }
__device__ inline float bhi(unsigned int u) { return __uint_as_float(u & 0xffff0000u); }
__device__ inline unsigned short f2b(float f) {
    unsigned int u = __float_as_uint(f);
    return (unsigned short)((u + 0x7FFFu + ((u >> 16) & 1u)) >> 16);
}
__device__ inline unsigned int packb(float lo, float hi) {
    return (unsigned int)f2b(lo) | ((unsigned int)f2b(hi) << 16);
}

__global__ void init_deg_cnt(float* __restrict__ wdeg, int* __restrict__ cnt, int n, float fill) {
    int i = blockIdx.x * blockDim.x + threadIdx.x;
    if (i < n) { wdeg[i] = fill; cnt[i] = 0; }
}

__global__ void accum_deg_cnt(const int* __restrict__ row, const float* __restrict__ w,
                              float* __restrict__ wdeg, int* __restrict__ cnt, int E) {
    int e = blockIdx.x * blockDim.x + threadIdx.x;
    if (e < E) {
        int r = row[e];
        atomicAdd(&wdeg[r], w[e]);
        atomicAdd(&cnt[r], 1);
    }
}

__global__ void finalize_dinv(float* __restrict__ wdeg, int n) {
    int i = blockIdx.x * blockDim.x + threadIdx.x;
    if (i < n) {
        float d = wdeg[i];
        wdeg[i] = d > 0.0f ? rsqrtf(d) : 0.0f;
    }
}

__global__ void convert_bf16(const float* __restrict__ x, unsigned short* __restrict__ xb, long nElem) {
    long t = (long)blockIdx.x * blockDim.x + threadIdx.x;
    long i = t * 4;
    if (i + 3 < nElem) {
        float4 v = *(const float4*)(x + i);
        ushort4 o;
        o.x = f2b(v.x); o.y = f2b(v.y); o.z = f2b(v.z); o.w = f2b(v.w);
        *(ushort4*)(xb + i) = o;
    } else {
        for (long k = i; k < nElem; ++k) xb[k] = f2b(x[k]);
    }
}

__global__ void scan_block_sums(const int* __restrict__ cnt, int* __restrict__ bsums, int n) {
    __shared__ int s[256];
    int t = threadIdx.x;
    int i = blockIdx.x * 256 + t;
    s[t] = (i < n) ? cnt[i] : 0;
    __syncthreads();
    for (int st = 128; st > 0; st >>= 1) {
        if (t < st) s[t] += s[t + st];
        __syncthreads();
    }
    if (t == 0) bsums[blockIdx.x] = s[0];
}

__global__ void scan_bsums(int* __restrict__ bsums, int nb) {
    __shared__ int s[1024];
    int t = threadIdx.x;
    s[t] = (t < nb) ? bsums[t] : 0;
    __syncthreads();
    for (int off = 1; off < 1024; off <<= 1) {
        int v = 0;
        if (t >= off) v = s[t - off];
        __syncthreads();
        if (t >= off) s[t] += v;
        __syncthreads();
    }
    if (t < nb) bsums[t] = (t == 0) ? 0 : s[t - 1];
}

__global__ void scan_final(const int* __restrict__ cnt, const int* __restrict__ bsums,
                           int* __restrict__ off, int* __restrict__ cur, int n) {
    __shared__ int s[256];
    int t = threadIdx.x;
    int i = blockIdx.x * 256 + t;
    int v = (i < n) ? cnt[i] : 0;
    s[t] = v;
    __syncthreads();
    for (int o = 1; o < 256; o <<= 1) {
        int u = 0;
        if (t >= o) u = s[t - o];
        __syncthreads();
        if (t >= o) s[t] += u;
        __syncthreads();
    }
    if (i < n) {
        int o0 = bsums[blockIdx.x] + s[t] - v;
        off[i] = o0;
        cur[i] = o0;
    }
}

// packed CSR entry: .x = col, .y = bits of pre-normalized weight
__global__ void scatter_csr(const int* __restrict__ row, const int* __restrict__ col,
                            const float* __restrict__ w, const float* __restrict__ dinv,
                            int* __restrict__ cur, uint2* __restrict__ csr, int E) {
    int e = blockIdx.x * blockDim.x + threadIdx.x;
    if (e >= E) return;
    int r = row[e];
    int c = col[e];
    int pos = atomicAdd(&cur[r], 1);
    uint2 ent;
    ent.x = (unsigned int)c;
    ent.y = __float_as_uint(dinv[r] * w[e] * dinv[c]);
    csr[pos] = ent;
}

// One wave per node; 8 edge-groups x 8 lanes, lane gathers uint4 = 8 bf16 cols.
// ALL up-to-8 gather loads of a 64-edge tile are issued before any FMA
// (static v[8] array, fully unrolled -> stays in VGPRs, 8 misses in flight).
#define GATHER_BODY(SRC)                                                        \
    int g = lane >> 3;                                                          \
    int q = lane & 7;                                                           \
    const unsigned int* xw = (const unsigned int*)(SRC);                        \
    float a0=0,a1=0,a2=0,a3=0,a4=0,a5=0,a6=0,a7=0;                              \
    int s = off[i], e = end[i];                                                 \
    float di = dinv[i];                                                         \
    uint4 sv = *(const uint4*)(xw + (long)i * 32 + q * 4);                      \
    for (int base = s; base < e; base += 64) {                                  \
        int m = e - base; if (m > 64) m = 64;                                   \
        int li = lane < m ? lane : m - 1;                                       \
        uint2 ent = csr[base + li];                                             \
        int cols = (int)ent.x;                                                  \
        float wsv = __uint_as_float(ent.y);                                     \
        uint4 v[8];                                                             \
        float wv[8];                                                            \
        _Pragma("unroll")                                                       \
        for (int p8 = 0; p8 < 8; ++p8) {                                        \
            int idx = p8 * 8 + g;                                               \
            int srcl = idx < m ? idx : m - 1;                                   \
            int c = __shfl(cols, srcl, 64);                                     \
            float wvv = __shfl(wsv, srcl, 64);                                  \
            if (idx >= m) wvv = 0.0f;                                           \
            wv[p8] = wvv;                                                       \
            if (p8 * 8 < m) v[p8] = *(const uint4*)(xw + (long)c * 32 + q * 4); \
        }                                                                       \
        _Pragma("unroll")                                                       \
        for (int p8 = 0; p8 < 8; ++p8) {                                        \
            if (p8 * 8 < m) {                                                   \
                float wvv = wv[p8];                                             \
                a0 += blo(v[p8].x) * wvv; a1 += bhi(v[p8].x) * wvv;             \
                a2 += blo(v[p8].y) * wvv; a3 += bhi(v[p8].y) * wvv;             \
                a4 += blo(v[p8].z) * wvv; a5 += bhi(v[p8].z) * wvv;             \
                a6 += blo(v[p8].w) * wvv; a7 += bhi(v[p8].w) * wvv;             \
            }                                                                   \
        }                                                                       \
    }                                                                           \
    a0 += __shfl_xor(a0, 8, 64); a0 += __shfl_xor(a0, 16, 64); a0 += __shfl_xor(a0, 32, 64); \
    a1 += __shfl_xor(a1, 8, 64); a1 += __shfl_xor(a1, 16, 64); a1 += __shfl_xor(a1, 32, 64); \
    a2 += __shfl_xor(a2, 8, 64); a2 += __shfl_xor(a2, 16, 64); a2 += __shfl_xor(a2, 32, 64); \
    a3 += __shfl_xor(a3, 8, 64); a3 += __shfl_xor(a3, 16, 64); a3 += __shfl_xor(a3, 32, 64); \
    a4 += __shfl_xor(a4, 8, 64); a4 += __shfl_xor(a4, 16, 64); a4 += __shfl_xor(a4, 32, 64); \
    a5 += __shfl_xor(a5, 8, 64); a5 += __shfl_xor(a5, 16, 64); a5 += __shfl_xor(a5, 32, 64); \
    a6 += __shfl_xor(a6, 8, 64); a6 += __shfl_xor(a6, 16, 64); a6 += __shfl_xor(a6, 32, 64); \
    a7 += __shfl_xor(a7, 8, 64); a7 += __shfl_xor(a7, 16, 64); a7 += __shfl_xor(a7, 32, 64); \
    float di2 = di * di;                                                        \
    a0 += blo(sv.x) * di2; a1 += bhi(sv.x) * di2;                               \
    a2 += blo(sv.y) * di2; a3 += bhi(sv.y) * di2;                               \
    a4 += blo(sv.z) * di2; a5 += bhi(sv.z) * di2;                               \
    a6 += blo(sv.w) * di2; a7 += bhi(sv.w) * di2;

__global__ void hop_gather_b(const unsigned short* __restrict__ xb, const float* __restrict__ dinv,
                             const int* __restrict__ off, const int* __restrict__ end,
                             const uint2* __restrict__ csr,
                             unsigned short* __restrict__ h1b, int n) {
    int t = blockIdx.x * blockDim.x + threadIdx.x;
    int i = t >> 6, lane = t & 63;
    if (i >= n) return;
    GATHER_BODY(xb)
    if (lane < 8) {
        uint4 o;
        o.x = packb(a0, a1); o.y = packb(a2, a3);
        o.z = packb(a4, a5); o.w = packb(a6, a7);
        *(uint4*)((unsigned int*)h1b + (long)i * 32 + q * 4) = o;
    }
}

__global__ void hop_gather_proj_b(const unsigned short* __restrict__ h1b, const float* __restrict__ dinv,
                                  const int* __restrict__ off, const int* __restrict__ end,
                                  const uint2* __restrict__ csr,
                                  const float* __restrict__ W, const float* __restrict__ bias,
                                  float* __restrict__ out, int n) {
    __shared__ float Wl[D * D];
    __shared__ float bl[D];
    for (int k = threadIdx.x; k < D * D; k += blockDim.x) Wl[k] = W[k];
    if (threadIdx.x < D) bl[threadIdx.x] = bias[threadIdx.x];
    __syncthreads();

    int t = blockIdx.x * blockDim.x + threadIdx.x;
    int i = t >> 6, lane = t & 63;
    if (i >= n) return;
    GATHER_BODY(h1b)

    // lane q2 (0..7) holds columns 8*q2+j in a_j; broadcast and project.
    float y = bl[lane];
    #pragma unroll
    for (int q2 = 0; q2 < 8; ++q2) {
        y += __shfl(a0, q2, 64) * Wl[(8 * q2 + 0) * D + lane];
        y += __shfl(a1, q2, 64) * Wl[(8 * q2 + 1) * D + lane];
        y += __shfl(a2, q2, 64) * Wl[(8 * q2 + 2) * D + lane];
        y += __shfl(a3, q2, 64) * Wl[(8 * q2 + 3) * D + lane];
        y += __shfl(a4, q2, 64) * Wl[(8 * q2 + 4) * D + lane];
        y += __shfl(a5, q2, 64) * Wl[(8 * q2 + 5) * D + lane];
        y += __shfl(a6, q2, 64) * Wl[(8 * q2 + 6) * D + lane];
        y += __shfl(a7, q2, 64) * Wl[(8 * q2 + 7) * D + lane];
    }
    out[(long)i * D + lane] = y;
}

extern "C" void kernel_launch(void* const* d_in, const int* in_sizes, int n_in,
                              void* d_out, int out_size, void* d_ws, size_t ws_size,
                              hipStream_t stream) {
    const float* x    = (const float*)d_in[0];
    const int*   ei   = (const int*)d_in[1];
    const float* ew   = (const float*)d_in[2];
    const float* W    = (const float*)d_in[3];
    const float* bias = (const float*)d_in[4];

    int n = in_sizes[0] / D;   // 100000
    int E = in_sizes[2];       // 1600000
    const int* row = ei;
    const int* col = ei + E;

    float* out = (float*)d_out;

    float* wdeg    = (float*)d_ws;                   // n (becomes dinv)
    int*   cnt     = (int*)(wdeg + alignup(n));      // n
    int*   bsums   = cnt + alignup(n);               // <=1024
    int*   off     = bsums + 1024;                   // n
    int*   cur     = off + alignup(n);               // n (becomes segment end)
    uint2* csr     = (uint2*)(cur + alignup(n));     // E x 8B (col, w)
    unsigned short* xb  = (unsigned short*)(csr + alignup(E)); // n*D bf16
    unsigned short* h1b = xb + (long)alignup(n) * D;           // n*D bf16

    const float fill = 1.0f;  // IMPROVED = False
    const int blk = 256;
    int nbN = (n + blk - 1) / blk;
    int nbE = (E + blk - 1) / blk;

    init_deg_cnt<<<nbN, blk, 0, stream>>>(wdeg, cnt, n, fill);
    accum_deg_cnt<<<nbE, blk, 0, stream>>>(row, ew, wdeg, cnt, E);
    finalize_dinv<<<nbN, blk, 0, stream>>>(wdeg, n);

    long nElem = (long)n * D;
    int nbC = (int)((nElem / 4 + blk - 1) / blk);
    convert_bf16<<<nbC, blk, 0, stream>>>(x, xb, nElem);

    scan_block_sums<<<nbN, blk, 0, stream>>>(cnt, bsums, n);
    scan_bsums<<<1, 1024, 0, stream>>>(bsums, nbN);
    scan_final<<<nbN, blk, 0, stream>>>(cnt, bsums, off, cur, n);

    scatter_csr<<<nbE, blk, 0, stream>>>(row, col, ew, wdeg, cur, csr, E);

    int nbWave = (int)((nElem + blk - 1) / blk);
    hop_gather_b<<<nbWave, blk, 0, stream>>>(xb, wdeg, off, cur, csr, h1b, n);
    hop_gather_proj_b<<<nbWave, blk, 0, stream>>>(h1b, wdeg, off, cur, csr,
                                                  W, bias, out, n);
}

// Round 7
// 418.122 us; speedup vs baseline: 1.1359x; 1.0685x over previous
//
#include <hip/hip_runtime.h>

#define D 64

static __host__ __device__ inline int alignup(int x) { return (x + 63) & ~63; }

__device__ inline float blo(unsigned int u) { return __uint_as_float(u << 16); }
__device__ inline float bhi(unsigned int u) { return __uint_as_float(u & 0xffff0000u); }
__device__ inline unsigned short f2b(float f) {
    unsigned int u = __float_as_uint(f);
    return (unsigned short)((u + 0x7FFFu + ((u >> 16) & 1u)) >> 16);
}
__device__ inline unsigned int packb(float lo, float hi) {
    return (unsigned int)f2b(lo) | ((unsigned int)f2b(hi) << 16);
}

__global__ void init_deg_cnt(float* __restrict__ wdeg, int* __restrict__ cnt, int n, float fill) {
    int i = blockIdx.x * blockDim.x + threadIdx.x;
    if (i < n) { wdeg[i] = fill; cnt[i] = 0; }
}

__global__ void accum_deg_cnt(const int* __restrict__ row, const float* __restrict__ w,
                              float* __restrict__ wdeg, int* __restrict__ cnt, int E) {
    int e = blockIdx.x * blockDim.x + threadIdx.x;
    if (e < E) {
        int r = row[e];
        atomicAdd(&wdeg[r], w[e]);
        atomicAdd(&cnt[r], 1);
    }
}

__global__ void finalize_dinv(float* __restrict__ wdeg, int n) {
    int i = blockIdx.x * blockDim.x + threadIdx.x;
    if (i < n) {
        float d = wdeg[i];
        wdeg[i] = d > 0.0f ? rsqrtf(d) : 0.0f;
    }
}

__global__ void convert_bf16(const float* __restrict__ x, unsigned short* __restrict__ xb, long nElem) {
    long t = (long)blockIdx.x * blockDim.x + threadIdx.x;
    long i = t * 4;
    if (i + 3 < nElem) {
        float4 v = *(const float4*)(x + i);
        ushort4 o;
        o.x = f2b(v.x); o.y = f2b(v.y); o.z = f2b(v.z); o.w = f2b(v.w);
        *(ushort4*)(xb + i) = o;
    } else {
        for (long k = i; k < nElem; ++k) xb[k] = f2b(x[k]);
    }
}

__global__ void scan_block_sums(const int* __restrict__ cnt, int* __restrict__ bsums, int n) {
    __shared__ int s[256];
    int t = threadIdx.x;
    int i = blockIdx.x * 256 + t;
    s[t] = (i < n) ? cnt[i] : 0;
    __syncthreads();
    for (int st = 128; st > 0; st >>= 1) {
        if (t < st) s[t] += s[t + st];
        __syncthreads();
    }
    if (t == 0) bsums[blockIdx.x] = s[0];
}

__global__ void scan_bsums(int* __restrict__ bsums, int nb) {
    __shared__ int s[1024];
    int t = threadIdx.x;
    s[t] = (t < nb) ? bsums[t] : 0;
    __syncthreads();
    for (int off = 1; off < 1024; off <<= 1) {
        int v = 0;
        if (t >= off) v = s[t - off];
        __syncthreads();
        if (t >= off) s[t] += v;
        __syncthreads();
    }
    if (t < nb) bsums[t] = (t == 0) ? 0 : s[t - 1];
}

__global__ void scan_final(const int* __restrict__ cnt, const int* __restrict__ bsums,
                           int* __restrict__ off, int* __restrict__ cur, int n) {
    __shared__ int s[256];
    int t = threadIdx.x;
    int i = blockIdx.x * 256 + t;
    int v = (i < n) ? cnt[i] : 0;
    s[t] = v;
    __syncthreads();
    for (int o = 1; o < 256; o <<= 1) {
        int u = 0;
        if (t >= o) u = s[t - o];
        __syncthreads();
        if (t >= o) s[t] += u;
        __syncthreads();
    }
    if (i < n) {
        int o0 = bsums[blockIdx.x] + s[t] - v;
        off[i] = o0;
        cur[i] = o0;
    }
}

__global__ void scatter_csr(const int* __restrict__ row, const int* __restrict__ col,
                            const float* __restrict__ w, const float* __restrict__ dinv,
                            int* __restrict__ cur, uint2* __restrict__ csr, int E) {
    int e = blockIdx.x * blockDim.x + threadIdx.x;
    if (e >= E) return;
    int r = row[e];
    int c = col[e];
    int pos = atomicAdd(&cur[r], 1);
    uint2 ent;
    ent.x = (unsigned int)c;
    ent.y = __float_as_uint(dinv[r] * w[e] * dinv[c]);
    csr[pos] = ent;
}

// 8 nodes per wave: group g (8 lanes) owns node wave*8+g; lane q owns columns
// 8q..8q+7 (one uint4 of bf16). Per iteration: 8 CSR entries in one coalesced
// load, 8 USEFUL gathers batched into static v[8] (all in flight before FMAs).
// No cross-group reduction. F32OUT: write f32 (256B/node) else bf16 (128B/node).
template <bool F32OUT>
__global__ void hop_g8(const unsigned short* __restrict__ xb, const float* __restrict__ dinv,
                       const int* __restrict__ off, const int* __restrict__ end,
                       const uint2* __restrict__ csr,
                       unsigned short* __restrict__ outb, float* __restrict__ outf, int n) {
    int t = blockIdx.x * blockDim.x + threadIdx.x;
    int wave = t >> 6;
    int lane = t & 63;
    int g = lane >> 3, q = lane & 7;
    int i = wave * 8 + g;
    bool active = i < n;
    int ii = active ? i : n - 1;

    const unsigned int* xw = (const unsigned int*)xb;
    float di = dinv[ii];
    float di2 = di * di;
    uint4 sv = *(const uint4*)(xw + (long)ii * 32 + q * 4);  // self row
    float a0 = blo(sv.x) * di2, a1 = bhi(sv.x) * di2;
    float a2 = blo(sv.y) * di2, a3 = bhi(sv.y) * di2;
    float a4 = blo(sv.z) * di2, a5 = bhi(sv.z) * di2;
    float a6 = blo(sv.w) * di2, a7 = bhi(sv.w) * di2;

    int s = active ? off[ii] : 0;
    int e = active ? end[ii] : 0;

    for (int b = s; b < e; b += 8) {
        int cl = b + q; if (cl >= e) cl = e - 1;
        uint2 ent = csr[cl];
        uint4 v[8];
        float wv[8];
        #pragma unroll
        for (int j = 0; j < 8; ++j) {
            int c = __shfl((int)ent.x, g * 8 + j, 64);
            float wj = __uint_as_float(__shfl((int)ent.y, g * 8 + j, 64));
            wv[j] = (b + j < e) ? wj : 0.0f;
            v[j] = *(const uint4*)(xw + (long)c * 32 + q * 4);
        }
        #pragma unroll
        for (int j = 0; j < 8; ++j) {
            float wj = wv[j];
            a0 += blo(v[j].x) * wj; a1 += bhi(v[j].x) * wj;
            a2 += blo(v[j].y) * wj; a3 += bhi(v[j].y) * wj;
            a4 += blo(v[j].z) * wj; a5 += bhi(v[j].z) * wj;
            a6 += blo(v[j].w) * wj; a7 += bhi(v[j].w) * wj;
        }
    }

    if (!active) return;
    if (F32OUT) {
        float4 o0 = make_float4(a0, a1, a2, a3);
        float4 o1 = make_float4(a4, a5, a6, a7);
        float* dst = outf + (long)i * D + q * 8;
        *(float4*)dst = o0;
        *(float4*)(dst + 4) = o1;
    } else {
        uint4 o;
        o.x = packb(a0, a1); o.y = packb(a2, a3);
        o.z = packb(a4, a5); o.w = packb(a6, a7);
        *(uint4*)((unsigned int*)outb + (long)i * 32 + q * 4) = o;
    }
}

// in-place projection: out[i,:] = out[i,:] @ W + bias. One wave per row;
// row fully read (shfl broadcasts) before the write -> in-place safe.
__global__ void proj_inplace(float* __restrict__ h, const float* __restrict__ W,
                             const float* __restrict__ bias, int n) {
    __shared__ float Wl[D * D];
    __shared__ float bl[D];
    int tid = threadIdx.x;
    for (int k = tid; k < D * D; k += blockDim.x) Wl[k] = W[k];
    if (tid < D) bl[tid] = bias[tid];
    __syncthreads();

    int lane = tid & 63;
    int wave = tid >> 6;
    int wavesPerBlock = blockDim.x >> 6;
    long r = (long)blockIdx.x * wavesPerBlock + wave;
    if (r >= n) return;
    float hv = h[r * D + lane];
    float y = bl[lane];
    #pragma unroll
    for (int k = 0; k < D; ++k) {
        y += __shfl(hv, k, 64) * Wl[k * D + lane];
    }
    h[r * D + lane] = y;
}

extern "C" void kernel_launch(void* const* d_in, const int* in_sizes, int n_in,
                              void* d_out, int out_size, void* d_ws, size_t ws_size,
                              hipStream_t stream) {
    const float* x    = (const float*)d_in[0];
    const int*   ei   = (const int*)d_in[1];
    const float* ew   = (const float*)d_in[2];
    const float* W    = (const float*)d_in[3];
    const float* bias = (const float*)d_in[4];

    int n = in_sizes[0] / D;   // 100000
    int E = in_sizes[2];       // 1600000
    const int* row = ei;
    const int* col = ei + E;

    float* out = (float*)d_out;

    float* wdeg    = (float*)d_ws;                   // n (becomes dinv)
    int*   cnt     = (int*)(wdeg + alignup(n));      // n
    int*   bsums   = cnt + alignup(n);               // <=1024
    int*   off     = bsums + 1024;                   // n
    int*   cur     = off + alignup(n);               // n (becomes segment end)
    uint2* csr     = (uint2*)(cur + alignup(n));     // E x 8B (col, w)
    unsigned short* xb  = (unsigned short*)(csr + alignup(E)); // n*D bf16
    unsigned short* h1b = xb + (long)alignup(n) * D;           // n*D bf16

    const float fill = 1.0f;  // IMPROVED = False
    const int blk = 256;
    int nbN = (n + blk - 1) / blk;
    int nbE = (E + blk - 1) / blk;

    init_deg_cnt<<<nbN, blk, 0, stream>>>(wdeg, cnt, n, fill);
    accum_deg_cnt<<<nbE, blk, 0, stream>>>(row, ew, wdeg, cnt, E);
    finalize_dinv<<<nbN, blk, 0, stream>>>(wdeg, n);

    long nElem = (long)n * D;
    int nbC = (int)((nElem / 4 + blk - 1) / blk);
    convert_bf16<<<nbC, blk, 0, stream>>>(x, xb, nElem);

    scan_block_sums<<<nbN, blk, 0, stream>>>(cnt, bsums, n);
    scan_bsums<<<1, 1024, 0, stream>>>(bsums, nbN);
    scan_final<<<nbN, blk, 0, stream>>>(cnt, bsums, off, cur, n);

    scatter_csr<<<nbE, blk, 0, stream>>>(row, col, ew, wdeg, cur, csr, E);

    // hops: 8 nodes per wave
    int nWaves = (n + 7) / 8;
    int nbHop = (nWaves * 64 + blk - 1) / blk;
    hop_g8<false><<<nbHop, blk, 0, stream>>>(xb, wdeg, off, cur, csr, h1b, nullptr, n);
    hop_g8<true><<<nbHop, blk, 0, stream>>>(h1b, wdeg, off, cur, csr, nullptr, out, n);

    // projection in-place on out
    proj_inplace<<<(n + 3) / 4, blk, 0, stream>>>(out, W, bias, n);
}

// Round 8
// 321.736 us; speedup vs baseline: 1.4762x; 1.2996x over previous
//
#include <hip/hip_runtime.h>

#define D 64

static __host__ __device__ inline int alignup(int x) { return (x + 63) & ~63; }

__device__ inline float blo(unsigned int u) { return __uint_as_float(u << 16); }
__device__ inline float bhi(unsigned int u) { return __uint_as_float(u & 0xffff0000u); }
__device__ inline unsigned short f2b(float f) {
    unsigned int u = __float_as_uint(f);
    return (unsigned short)((u + 0x7FFFu + ((u >> 16) & 1u)) >> 16);
}
__device__ inline unsigned int packb(float lo, float hi) {
    return (unsigned int)f2b(lo) | ((unsigned int)f2b(hi) << 16);
}

__global__ void init_cnt(int* __restrict__ cnt, int n) {
    int i = blockIdx.x * blockDim.x + threadIdx.x;
    if (i < n) cnt[i] = 0;
}

// ONE atomic per edge: slot position within row + final counts.
__global__ void histo_pos(const int* __restrict__ row, int* __restrict__ cnt,
                          int* __restrict__ aux, int E) {
    int e = blockIdx.x * blockDim.x + threadIdx.x;
    if (e < E) aux[e] = atomicAdd(&cnt[row[e]], 1);
}

__global__ void convert_bf16(const float* __restrict__ x, unsigned short* __restrict__ xb, long nElem) {
    long t = (long)blockIdx.x * blockDim.x + threadIdx.x;
    long i = t * 4;
    if (i + 3 < nElem) {
        float4 v = *(const float4*)(x + i);
        ushort4 o;
        o.x = f2b(v.x); o.y = f2b(v.y); o.z = f2b(v.z); o.w = f2b(v.w);
        *(ushort4*)(xb + i) = o;
    } else {
        for (long k = i; k < nElem; ++k) xb[k] = f2b(x[k]);
    }
}

__global__ void scan_block_sums(const int* __restrict__ cnt, int* __restrict__ bsums, int n) {
    __shared__ int s[256];
    int t = threadIdx.x;
    int i = blockIdx.x * 256 + t;
    s[t] = (i < n) ? cnt[i] : 0;
    __syncthreads();
    for (int st = 128; st > 0; st >>= 1) {
        if (t < st) s[t] += s[t + st];
        __syncthreads();
    }
    if (t == 0) bsums[blockIdx.x] = s[0];
}

__global__ void scan_bsums(int* __restrict__ bsums, int nb) {
    __shared__ int s[1024];
    int t = threadIdx.x;
    s[t] = (t < nb) ? bsums[t] : 0;
    __syncthreads();
    for (int off = 1; off < 1024; off <<= 1) {
        int v = 0;
        if (t >= off) v = s[t - off];
        __syncthreads();
        if (t >= off) s[t] += v;
        __syncthreads();
    }
    if (t < nb) bsums[t] = (t == 0) ? 0 : s[t - 1];
}

// writes off[i] (exclusive prefix) and end[i] = off[i] + cnt[i]
__global__ void scan_final(const int* __restrict__ cnt, const int* __restrict__ bsums,
                           int* __restrict__ off, int* __restrict__ end, int n) {
    __shared__ int s[256];
    int t = threadIdx.x;
    int i = blockIdx.x * 256 + t;
    int v = (i < n) ? cnt[i] : 0;
    s[t] = v;
    __syncthreads();
    for (int o = 1; o < 256; o <<= 1) {
        int u = 0;
        if (t >= o) u = s[t - o];
        __syncthreads();
        if (t >= o) s[t] += u;
        __syncthreads();
    }
    if (i < n) {
        int o0 = bsums[blockIdx.x] + s[t] - v;
        off[i] = o0;
        end[i] = o0 + v;
    }
}

// atomic-free scatter: position known from histo. Stores RAW weight bits.
__global__ void reorder_csr(const int* __restrict__ row, const int* __restrict__ col,
                            const float* __restrict__ w, const int* __restrict__ off,
                            const int* __restrict__ aux, uint2* __restrict__ csr, int E) {
    int e = blockIdx.x * blockDim.x + threadIdx.x;
    if (e >= E) return;
    int r = row[e];
    uint2 ent;
    ent.x = (unsigned int)col[e];
    ent.y = __float_as_uint(w[e]);
    csr[off[r] + aux[e]] = ent;
}

// per-node: wdeg = fill + segment sum of raw w -> dinv = rsqrt
__global__ void seg_dinv(const uint2* __restrict__ csr, const int* __restrict__ off,
                         const int* __restrict__ end, float* __restrict__ dinv,
                         int n, float fill) {
    int i = blockIdx.x * blockDim.x + threadIdx.x;
    if (i >= n) return;
    float d = fill;
    int s = off[i], e = end[i];
    for (int p = s; p < e; ++p) d += __uint_as_float(csr[p].y);
    dinv[i] = d > 0.0f ? rsqrtf(d) : 0.0f;
}

// fold dinv[r]*dinv[c] into stored weights (dinv is L2-resident, 400KB)
__global__ void norm_w(uint2* __restrict__ csr, const int* __restrict__ off,
                       const int* __restrict__ end, const float* __restrict__ dinv, int n) {
    int i = blockIdx.x * blockDim.x + threadIdx.x;
    if (i >= n) return;
    float di = dinv[i];
    int s = off[i], e = end[i];
    for (int p = s; p < e; ++p) {
        uint2 ent = csr[p];
        float wn = __uint_as_float(ent.y) * di * dinv[(int)ent.x];
        ((float*)csr)[2 * p + 1] = wn;
    }
}

// 8 nodes per wave; group g (8 lanes) owns node wave*8+g; lane q owns columns
// 8q..8q+7. 16 entries per iteration: two coalesced uint2 loads, all 16
// gathers issued into static v[16] before any FMA (zero-weight gathers masked).
template <bool F32OUT>
__global__ void hop_g8(const unsigned short* __restrict__ xb, const float* __restrict__ dinv,
                       const int* __restrict__ off, const int* __restrict__ end,
                       const uint2* __restrict__ csr,
                       unsigned short* __restrict__ outb, float* __restrict__ outf, int n) {
    int t = blockIdx.x * blockDim.x + threadIdx.x;
    int wave = t >> 6;
    int lane = t & 63;
    int g = lane >> 3, q = lane & 7;
    int i = wave * 8 + g;
    bool active = i < n;
    int ii = active ? i : n - 1;

    const unsigned int* xw = (const unsigned int*)xb;
    float di = dinv[ii];
    float di2 = di * di;  // self-loop weight (fill=1): dinv^2
    uint4 sv = *(const uint4*)(xw + (long)ii * 32 + q * 4);
    float a0 = blo(sv.x) * di2, a1 = bhi(sv.x) * di2;
    float a2 = blo(sv.y) * di2, a3 = bhi(sv.y) * di2;
    float a4 = blo(sv.z) * di2, a5 = bhi(sv.z) * di2;
    float a6 = blo(sv.w) * di2, a7 = bhi(sv.w) * di2;

    int s = active ? off[ii] : 0;
    int e = active ? end[ii] : 0;

    for (int b = s; b < e; b += 16) {
        int i0 = b + q;     if (i0 >= e) i0 = e - 1;
        int i1 = b + 8 + q; if (i1 >= e) i1 = e - 1;
        uint2 e0 = csr[i0];
        uint2 e1 = csr[i1];
        uint4 v[16];
        float wv[16];
        #pragma unroll
        for (int j = 0; j < 16; ++j) {
            int srcl = g * 8 + (j & 7);
            int cb = __shfl((int)(j < 8 ? e0.x : e1.x), srcl, 64);
            float wj = __uint_as_float(__shfl((int)(j < 8 ? e0.y : e1.y), srcl, 64));
            if (b + j >= e) wj = 0.0f;
            wv[j] = wj;
            v[j] = make_uint4(0u, 0u, 0u, 0u);
            if (wj != 0.0f) v[j] = *(const uint4*)(xw + (long)cb * 32 + q * 4);
        }
        #pragma unroll
        for (int j = 0; j < 16; ++j) {
            float wj = wv[j];
            a0 += blo(v[j].x) * wj; a1 += bhi(v[j].x) * wj;
            a2 += blo(v[j].y) * wj; a3 += bhi(v[j].y) * wj;
            a4 += blo(v[j].z) * wj; a5 += bhi(v[j].z) * wj;
            a6 += blo(v[j].w) * wj; a7 += bhi(v[j].w) * wj;
        }
    }

    if (!active) return;
    if (F32OUT) {
        float* dst = outf + (long)i * D + q * 8;
        *(float4*)dst = make_float4(a0, a1, a2, a3);
        *(float4*)(dst + 4) = make_float4(a4, a5, a6, a7);
    } else {
        uint4 o;
        o.x = packb(a0, a1); o.y = packb(a2, a3);
        o.z = packb(a4, a5); o.w = packb(a6, a7);
        *(uint4*)((unsigned int*)outb + (long)i * 32 + q * 4) = o;
    }
}

// in-place projection: out[i,:] = out[i,:] @ W + bias (row read before write)
__global__ void proj_inplace(float* __restrict__ h, const float* __restrict__ W,
                             const float* __restrict__ bias, int n) {
    __shared__ float Wl[D * D];
    __shared__ float bl[D];
    int tid = threadIdx.x;
    for (int k = tid; k < D * D; k += blockDim.x) Wl[k] = W[k];
    if (tid < D) bl[tid] = bias[tid];
    __syncthreads();

    int lane = tid & 63;
    int wave = tid >> 6;
    int wavesPerBlock = blockDim.x >> 6;
    long r = (long)blockIdx.x * wavesPerBlock + wave;
    if (r >= n) return;
    float hv = h[r * D + lane];
    float y = bl[lane];
    #pragma unroll
    for (int k = 0; k < D; ++k) {
        y += __shfl(hv, k, 64) * Wl[k * D + lane];
    }
    h[r * D + lane] = y;
}

extern "C" void kernel_launch(void* const* d_in, const int* in_sizes, int n_in,
                              void* d_out, int out_size, void* d_ws, size_t ws_size,
                              hipStream_t stream) {
    const float* x    = (const float*)d_in[0];
    const int*   ei   = (const int*)d_in[1];
    const float* ew   = (const float*)d_in[2];
    const float* W    = (const float*)d_in[3];
    const float* bias = (const float*)d_in[4];

    int n = in_sizes[0] / D;   // 100000
    int E = in_sizes[2];       // 1600000
    const int* row = ei;
    const int* col = ei + E;

    float* out = (float*)d_out;

    // workspace layout (4-byte units)
    float* dinv  = (float*)d_ws;                  // n
    int*   cnt   = (int*)(dinv + alignup(n));     // n
    int*   bsums = cnt + alignup(n);              // <=1024
    int*   off   = bsums + 1024;                  // n
    int*   endp  = off + alignup(n);              // n
    int*   aux   = endp + alignup(n);             // E
    uint2* csr   = (uint2*)(aux + alignup(E));    // E x 8B
    unsigned short* xb  = (unsigned short*)(csr + alignup(E)); // n*D bf16
    unsigned short* h1b = xb + (long)alignup(n) * D;           // n*D bf16

    const float fill = 1.0f;  // IMPROVED = False
    const int blk = 256;
    int nbN = (n + blk - 1) / blk;
    int nbE = (E + blk - 1) / blk;

    init_cnt<<<nbN, blk, 0, stream>>>(cnt, n);
    histo_pos<<<nbE, blk, 0, stream>>>(row, cnt, aux, E);

    long nElem = (long)n * D;
    int nbC = (int)((nElem / 4 + blk - 1) / blk);
    convert_bf16<<<nbC, blk, 0, stream>>>(x, xb, nElem);

    scan_block_sums<<<nbN, blk, 0, stream>>>(cnt, bsums, n);
    scan_bsums<<<1, 1024, 0, stream>>>(bsums, nbN);
    scan_final<<<nbN, blk, 0, stream>>>(cnt, bsums, off, endp, n);

    reorder_csr<<<nbE, blk, 0, stream>>>(row, col, ew, off, aux, csr, E);
    seg_dinv<<<nbN, blk, 0, stream>>>(csr, off, endp, dinv, n, fill);
    norm_w<<<nbN, blk, 0, stream>>>(csr, off, endp, dinv, n);

    int nWaves = (n + 7) / 8;
    int nbHop = (nWaves * 64 + blk - 1) / blk;
    hop_g8<false><<<nbHop, blk, 0, stream>>>(xb, dinv, off, endp, csr, h1b, nullptr, n);
    hop_g8<true><<<nbHop, blk, 0, stream>>>(h1b, dinv, off, endp, csr, nullptr, out, n);

    proj_inplace<<<(n + 3) / 4, blk, 0, stream>>>(out, W, bias, n);
}